// Round 3
// baseline (538.580 us; speedup 1.0000x reference)
//
#include <hip/hip_runtime.h>
#include <hip/hip_cooperative_groups.h>

namespace cg = cooperative_groups;

typedef _Float16 half2_t __attribute__((ext_vector_type(2)));
typedef unsigned int uint;

#define D 128
#define O 64
#define UNR 8
#define NPW 8      // nodes per wave in fallback hop
#define PNW 8      // nodes per wave in proj
#define NPW_MAX 18 // max nodes per wave in coop kernel (LDS budget: 4*18*64*4 = 18 KB)

static inline size_t align_up(size_t x, size_t a) { return (x + a - 1) & ~(a - 1); }

__device__ __forceinline__ uint pack_f16(float a, float b) {
  half2_t h;
  h.x = (_Float16)a;
  h.y = (_Float16)b;
  return *(uint*)&h;
}

__device__ __forceinline__ float dot2f(uint a, uint b, float c) {
#if defined(__has_builtin) && __has_builtin(__builtin_amdgcn_fdot2)
  return __builtin_amdgcn_fdot2(*(half2_t*)&a, *(half2_t*)&b, c, false);
#else
  half2_t ha = *(half2_t*)&a, hb = *(half2_t*)&b;
  return c + (float)ha.x * (float)hb.x + (float)ha.y * (float)hb.y;
#endif
}

// ---------------- setup kernels ----------------

__global__ void count_deg_k(const int* __restrict__ col, int* __restrict__ deg, int E, int n) {
  int i = blockIdx.x * blockDim.x + threadIdx.x;
  if (i >= E) return;
  int c = col[i];
  if ((unsigned)c >= (unsigned)n) return;
  atomicAdd(&deg[c], 1);
}

__global__ void scan1_k(const int* __restrict__ deg, int* __restrict__ row_ptr,
                        int* __restrict__ bsum, float* __restrict__ dinv, int n) {
  __shared__ int s[256];
  int tid = threadIdx.x;
  int gid = blockIdx.x * 256 + tid;
  int dg = (gid < n) ? deg[gid] : 0;
  if (gid < n) dinv[gid] = rsqrtf((float)(dg + 1));
  s[tid] = dg;
  __syncthreads();
  for (int off = 1; off < 256; off <<= 1) {
    int t = (tid >= off) ? s[tid - off] : 0;
    __syncthreads();
    s[tid] += t;
    __syncthreads();
  }
  if (gid < n) row_ptr[gid] = s[tid] - dg;  // block-local exclusive
  if (tid == 255) bsum[blockIdx.x] = s[255];
}

__global__ void scan2_k(int* __restrict__ bsum, int nb) {
  __shared__ int s[512];
  int tid = threadIdx.x;
  int v = (tid < nb) ? bsum[tid] : 0;
  s[tid] = v;
  __syncthreads();
  for (int off = 1; off < 512; off <<= 1) {
    int t = (tid >= off) ? s[tid - off] : 0;
    __syncthreads();
    s[tid] += t;
    __syncthreads();
  }
  if (tid < nb) bsum[tid] = s[tid] - v;
}

__global__ void scan3_k(const int* __restrict__ bsum, const int* __restrict__ deg,
                        int* __restrict__ row_ptr, int* __restrict__ cursor, int n) {
  int gid = blockIdx.x * 256 + threadIdx.x;
  if (gid < n) {
    int r = row_ptr[gid] + bsum[blockIdx.x];
    row_ptr[gid] = r;
    cursor[gid] = r;
    if (gid == n - 1) row_ptr[n] = r + deg[gid];
  }
}

__global__ void fill_k(const int* __restrict__ rows, const int* __restrict__ cols,
                       int* __restrict__ cursor, const float* __restrict__ dinv,
                       int2* __restrict__ csr, int E, int n) {
  int i = blockIdx.x * blockDim.x + threadIdx.x;
  if (i >= E) return;
  int u = rows[i], v = cols[i];
  if ((unsigned)v >= (unsigned)n) return;  // must match count_deg_k skip
  if ((unsigned)u >= (unsigned)n) u = 0;
  int slot = atomicAdd(&cursor[v], 1);
  float nrm = dinv[u] * dinv[v];
  csr[slot] = make_int2(u, __float_as_int(nrm));
}

// softmax over hop weights + pack W to f16x2, TRANSPOSED: Wpk[dd*64+o]
__global__ void prep_k(const float* __restrict__ t, float* __restrict__ tn,
                       const float* __restrict__ W, uint* __restrict__ Wpk, int step) {
  int tid = threadIdx.x;
  if (tid < D) {
    float vals[16];
    float m = -1e30f;
    for (int k = 0; k < step; ++k) { vals[k] = t[k * D + tid]; m = fmaxf(m, vals[k]); }
    float ssum = 0.f;
    for (int k = 0; k < step; ++k) { vals[k] = expf(vals[k] - m); ssum += vals[k]; }
    float inv = 1.f / ssum;
    for (int k = 0; k < step; ++k) tn[k * D + tid] = vals[k] * inv;
  }
  for (int i = tid; i < O * 64; i += 256) {
    int o = i & 63, dd = i >> 6;  // i = dd*64 + o
    Wpk[i] = pack_f16(W[o * D + 2 * dd], W[o * D + 2 * dd + 1]);
  }
}

__global__ void init_h_k(const float* __restrict__ x, uint* __restrict__ h0, int total) {
  int i = blockIdx.x * blockDim.x + threadIdx.x;
  if (i >= total) return;
  float2 v = ((const float2*)x)[i];
  h0[i] = pack_f16(v.x, v.y);
}

// ---------------- cooperative persistent kernel: init + 9 hops + y in LDS ----
// Each wave owns npw contiguous nodes for the WHOLE kernel. y accumulates in
// LDS (f16x2 per lane per node) across hops -> zero global y traffic until the
// single final writeout. grid.sync() between hops replaces kernel relaunch.
// No early returns: every thread reaches every grid.sync().

__global__ __launch_bounds__(256) void coop_hops_k(
    const float* __restrict__ x,
    uint* __restrict__ h_a, uint* __restrict__ h_b,
    const int* __restrict__ row_ptr, const int2* __restrict__ csr,
    const float* __restrict__ dinv, const float* __restrict__ tn,
    uint* __restrict__ ybuf, int n, int step, int npw) {
  cg::grid_group gg = cg::this_grid();
  __shared__ uint ylds[4 * NPW_MAX * 64];
  int tid = threadIdx.x;
  int lane = tid & 63;
  int wv = tid >> 6;
  int wid = blockIdx.x * 4 + wv;
  int v0 = wid * npw;
  int vN = v0 + npw;
  if (vN > n) vN = n;
  int blkBase = blockIdx.x * 4 * npw;

  // init: f16 h0 for own nodes, zero own y slots
  for (int v = v0; v < vN; ++v) {
    float2 xv = ((const float2*)x)[((size_t)v << 6) + lane];
    h_a[((size_t)v << 6) + lane] = pack_f16(xv.x, xv.y);
    ylds[((v - blkBase) << 6) + lane] = 0;
  }
  gg.sync();

  uint* ho = h_a;
  uint* hn = h_b;
  for (int k = 1; k < step; ++k) {
    bool pair = (k & 1) != 0;
    bool tail = !pair && (k == step - 1);  // only when step is odd
    if (v0 < n) {
      float2 ta = make_float2(0.f, 0.f), tb = make_float2(0.f, 0.f);
      if (pair) ta = ((const float2*)(tn + (size_t)(k - 1) * D))[lane];
      if (pair || tail) tb = ((const float2*)(tn + (size_t)k * D))[lane];
      for (int v = v0; v < vN; ++v) {
        float dv = dinv[v];
        float ns = dv * dv;  // self-loop norm
        uint hp = ho[((size_t)v << 6) + lane];
        half2_t hv = *(half2_t*)&hp;
        float hx = (float)hv.x, hy = (float)hv.y;
        float ax = ns * hx, ay = ns * hy;
        int beg = __builtin_amdgcn_readfirstlane(row_ptr[v]);
        int end = __builtin_amdgcn_readfirstlane(row_ptr[v + 1]);
        for (int i = beg; i < end; i += UNR) {
          int u[UNR];
          float w[UNR];
#pragma unroll
          for (int j = 0; j < UNR; ++j) {
            int ic = i + j;
            int icl = (ic < end - 1) ? ic : (end - 1);
            int2 e = csr[icl];
            u[j] = e.x;
            w[j] = (ic < end) ? __int_as_float(e.y) : 0.f;
          }
          uint g[UNR];
#pragma unroll
          for (int j = 0; j < UNR; ++j) g[j] = ho[((size_t)u[j] << 6) + lane];
#pragma unroll
          for (int j = 0; j < UNR; ++j) {
            half2_t h = *(half2_t*)&g[j];
            ax += w[j] * (float)h.x;
            ay += w[j] * (float)h.y;
          }
        }
        hn[((size_t)v << 6) + lane] = pack_f16(ax, ay);
        if (pair || tail) {
          int slot = ((v - blkBase) << 6) + lane;
          uint yo = ylds[slot];
          half2_t yh = *(half2_t*)&yo;
          float yx = (float)yh.x, yy = (float)yh.y;
          if (pair) {
            yx += ta.x * hx + tb.x * ax;
            yy += ta.y * hy + tb.y * ay;
          } else {
            yx += tb.x * ax;
            yy += tb.y * ay;
          }
          ylds[slot] = pack_f16(yx, yy);
        }
      }
    }
    gg.sync();
    uint* tmp = ho; ho = hn; hn = tmp;
  }

  // single y writeout
  for (int v = v0; v < vN; ++v)
    ybuf[((size_t)v << 6) + lane] = ylds[((v - blkBase) << 6) + lane];
}

// ---------------- fallback multi-node pipelined hop (R2, proven) -------------
// DO_Y: 0 none | 1 y = tp*h_old + tc*h_new | 2 y += pair | 3 y += tc*h_new

template <int DO_Y>
__global__ __launch_bounds__(256) void hop_m_k(
    const uint* __restrict__ hsrc, uint* __restrict__ hdst, uint* __restrict__ y,
    const int* __restrict__ row_ptr, const int2* __restrict__ csr,
    const float* __restrict__ dinv, const float* __restrict__ tprev,
    const float* __restrict__ tcur, int n) {
  int wid = (blockIdx.x * blockDim.x + threadIdx.x) >> 6;
  int lane = threadIdx.x & 63;
  int v0 = wid * NPW;
  if (v0 >= n) return;
  int vN = (v0 + NPW < n) ? v0 + NPW : n;

  float2 ta = make_float2(0.f, 0.f), tb = make_float2(0.f, 0.f);
  if (DO_Y) {
    if (DO_Y != 3) ta = ((const float2*)tprev)[lane];
    tb = ((const float2*)tcur)[lane];
  }
  for (int v = v0; v < vN; ++v) {
    float dv = dinv[v];
    float ns = dv * dv;
    uint hp = hsrc[((size_t)v << 6) + lane];
    half2_t hv = *(half2_t*)&hp;
    float hx = (float)hv.x, hy = (float)hv.y;
    float ax = ns * hx, ay = ns * hy;
    int beg = __builtin_amdgcn_readfirstlane(row_ptr[v]);
    int end = __builtin_amdgcn_readfirstlane(row_ptr[v + 1]);
    for (int i = beg; i < end; i += UNR) {
      int u[UNR];
      float w[UNR];
#pragma unroll
      for (int j = 0; j < UNR; ++j) {
        int ic = i + j;
        int icl = (ic < end - 1) ? ic : (end - 1);
        int2 e = csr[icl];
        u[j] = e.x;
        w[j] = (ic < end) ? __int_as_float(e.y) : 0.f;
      }
      uint g[UNR];
#pragma unroll
      for (int j = 0; j < UNR; ++j) g[j] = hsrc[((size_t)u[j] << 6) + lane];
#pragma unroll
      for (int j = 0; j < UNR; ++j) {
        half2_t h = *(half2_t*)&g[j];
        ax += w[j] * (float)h.x;
        ay += w[j] * (float)h.y;
      }
    }
    hdst[((size_t)v << 6) + lane] = pack_f16(ax, ay);
    if (DO_Y) {
      float yx, yy;
      if (DO_Y == 3) {
        yx = tb.x * ax; yy = tb.y * ay;
      } else {
        yx = ta.x * hx + tb.x * ax;
        yy = ta.y * hy + tb.y * ay;
      }
      if (DO_Y >= 2) {
        uint yo = y[((size_t)v << 6) + lane];
        half2_t yh = *(half2_t*)&yo;
        yx += (float)yh.x;
        yy += (float)yh.y;
      }
      y[((size_t)v << 6) + lane] = pack_f16(yx, yy);
    }
  }
}

// ---------------- proj from fused y: out = y @ W^T + b ----------------

__global__ __launch_bounds__(256) void proj_y2_k(
    const uint* __restrict__ y, const uint* __restrict__ Wpk,
    const float* __restrict__ b, float* __restrict__ out, int n) {
  __shared__ uint sy[4][64];
  int tid = threadIdx.x;
  int lane = tid & 63, wv = tid >> 6;
  uint wreg[64];
#pragma unroll
  for (int j = 0; j < 64; ++j) wreg[j] = Wpk[j * 64 + lane];  // coalesced (transposed)
  float bias = b[lane];
  int wid = (blockIdx.x * blockDim.x + tid) >> 6;
  int vb = wid * PNW;
  int ve = vb + PNW < n ? vb + PNW : n;
  for (int v = vb; v < ve; ++v) {
    sy[wv][lane] = y[(size_t)v * 64 + lane];  // wave-local broadcast buffer
    float acc = bias;
#pragma unroll
    for (int q = 0; q < 16; ++q) {
      uint4 yq = *(const uint4*)&sy[wv][q * 4];  // broadcast b128 read
      acc = dot2f(yq.x, wreg[q * 4 + 0], acc);
      acc = dot2f(yq.y, wreg[q * 4 + 1], acc);
      acc = dot2f(yq.z, wreg[q * 4 + 2], acc);
      acc = dot2f(yq.w, wreg[q * 4 + 3], acc);
    }
    out[(size_t)v * O + lane] = acc;
  }
}

// ---------------- launch ----------------

extern "C" void kernel_launch(void* const* d_in, const int* in_sizes, int n_in,
                              void* d_out, int out_size, void* d_ws, size_t ws_size,
                              hipStream_t stream) {
  const float* x = (const float*)d_in[0];
  const int* ei = (const int*)d_in[1];
  const float* t = (const float*)d_in[2];
  const float* W = (const float*)d_in[3];
  const float* b = (const float*)d_in[4];
  float* out = (float*)d_out;

  int n = in_sizes[0] / D;
  int E = in_sizes[1] / 2;
  int step = in_sizes[2] / D;  // = 10
  const int* rows = ei;        // sources
  const int* cols = ei + E;    // targets

  char* p = (char*)d_ws;
  auto alloc = [&](size_t bytes) { char* r = p; p += align_up(bytes, 256); return r; };
  int*   deg     = (int*)alloc((size_t)n * 4);
  float* dinv    = (float*)alloc((size_t)n * 4);
  int*   row_ptr = (int*)alloc((size_t)(n + 1) * 4);
  int*   cursor  = (int*)alloc((size_t)n * 4);
  int*   bsum    = (int*)alloc(2048);
  int2*  csr     = (int2*)alloc((size_t)E * 8);
  float* tn      = (float*)alloc((size_t)step * D * 4);
  uint*  Wpk     = (uint*)alloc((size_t)O * 64 * 4);

  size_t NS = (size_t)n * 64;  // uints per h buffer
  uint* h_a  = (uint*)alloc(NS * 4);
  uint* h_b  = (uint*)alloc(NS * 4);
  uint* ybuf = (uint*)alloc(NS * 4);

  // ---- setup ----
  hipMemsetAsync(deg, 0, (size_t)n * 4, stream);
  int nb1 = (n + 255) / 256;
  count_deg_k<<<(E + 255) / 256, 256, 0, stream>>>(cols, deg, E, n);
  scan1_k<<<nb1, 256, 0, stream>>>(deg, row_ptr, bsum, dinv, n);
  scan2_k<<<1, 512, 0, stream>>>(bsum, nb1);
  scan3_k<<<nb1, 256, 0, stream>>>(bsum, deg, row_ptr, cursor, n);
  fill_k<<<(E + 255) / 256, 256, 0, stream>>>(rows, cols, cursor, dinv, csr, E, n);
  prep_k<<<1, 256, 0, stream>>>(t, tn, W, Wpk, step);

  // ---- cooperative grid sizing (one-time host queries; no stream ops) ----
  static int g_blocks = -2;  // -2 = unqueried, -1 = coop unavailable
  if (g_blocks == -2) {
    int coop = 0, dev = 0;
    hipGetDevice(&dev);
    if (hipDeviceGetAttribute(&coop, hipDeviceAttributeCooperativeLaunch, dev) != hipSuccess)
      coop = 0;
    if (!coop) {
      g_blocks = -1;
    } else {
      int perCU = 0, nCU = 0;
      hipDeviceGetAttribute(&nCU, hipDeviceAttributeMultiprocessorCount, dev);
      hipError_t e = hipOccupancyMaxActiveBlocksPerMultiprocessor(
          &perCU, reinterpret_cast<const void*>(coop_hops_k), 256, 0);
      g_blocks = (e == hipSuccess && perCU > 0 && nCU > 0) ? perCU * nCU : -1;
    }
  }

  int npw = (g_blocks > 0) ? (n + g_blocks * 4 - 1) / (g_blocks * 4) : 0;
  bool use_coop = (g_blocks > 0) && (npw >= 1) && (npw <= NPW_MAX) && (step >= 2) && (step <= 16);

  int proj_blocks = (n + PNW * 4 - 1) / (PNW * 4);

  if (use_coop) {
    void* kargs[] = {(void*)&x,   (void*)&h_a, (void*)&h_b,  (void*)&row_ptr,
                     (void*)&csr, (void*)&dinv, (void*)&tn,  (void*)&ybuf,
                     (void*)&n,   (void*)&step, (void*)&npw};
    hipLaunchCooperativeKernel(reinterpret_cast<void*>(coop_hops_k),
                               dim3(g_blocks), dim3(256), kargs, 0, stream);
  } else {
    // fallback: proven R2 multi-kernel path
    int hop_blocks = (n + NPW * 4 - 1) / (NPW * 4);
    init_h_k<<<((size_t)NS + 255) / 256, 256, 0, stream>>>(x, h_a, (int)NS);
    uint* ho = h_a;
    uint* hn = h_b;
    for (int k = 1; k < step; ++k) {
      const float* tp = tn + (size_t)(k - 1) * D;
      const float* tc = tn + (size_t)k * D;
      if (k & 1) {
        if (k == 1)
          hop_m_k<1><<<hop_blocks, 256, 0, stream>>>(ho, hn, ybuf, row_ptr, csr, dinv, tp, tc, n);
        else
          hop_m_k<2><<<hop_blocks, 256, 0, stream>>>(ho, hn, ybuf, row_ptr, csr, dinv, tp, tc, n);
      } else if (k == step - 1) {
        hop_m_k<3><<<hop_blocks, 256, 0, stream>>>(ho, hn, ybuf, row_ptr, csr, dinv, tp, tc, n);
      } else {
        hop_m_k<0><<<hop_blocks, 256, 0, stream>>>(ho, hn, ybuf, row_ptr, csr, dinv, tp, tc, n);
      }
      uint* tmp = ho; ho = hn; hn = tmp;
    }
  }

  proj_y2_k<<<proj_blocks, 256, 0, stream>>>(ybuf, Wpk, b, out, n);
}

// Round 4
// 530.950 us; speedup vs baseline: 1.0144x; 1.0144x over previous
//
#include <hip/hip_runtime.h>

typedef _Float16 half2_t __attribute__((ext_vector_type(2)));
typedef unsigned int uint;
typedef unsigned long long ull;

#define D 128
#define O 64
#define UNR 8
#define PNW 8   // nodes per wave in proj
#define MAX_SCAN_BLOCKS 2000  // co-residency guard for lookback scan (8 blk/CU * 256 CU)

static inline size_t align_up(size_t x, size_t a) { return (x + a - 1) & ~(a - 1); }

__device__ __forceinline__ uint pack_f16(float a, float b) {
  half2_t h;
  h.x = (_Float16)a;
  h.y = (_Float16)b;
  return *(uint*)&h;
}

__device__ __forceinline__ float dot2f(uint a, uint b, float c) {
#if defined(__has_builtin) && __has_builtin(__builtin_amdgcn_fdot2)
  return __builtin_amdgcn_fdot2(*(half2_t*)&a, *(half2_t*)&b, c, false);
#else
  half2_t ha = *(half2_t*)&a, hb = *(half2_t*)&b;
  return c + (float)ha.x * (float)hb.x + (float)ha.y * (float)hb.y;
#endif
}

// ---------------- fused setup mega-kernel ----------------
// Block ranges: [0, ib)          : x -> f16 h0        (init_h)
//               [ib, ib+eb)      : degree count        (count_deg)
//               [ib+eb]          : softmax(t) + pack W (prep)
// The three are mutually independent; fusing removes 2 dispatch gaps.

__global__ __launch_bounds__(256) void setup_k(
    const float* __restrict__ x, uint* __restrict__ h0, int totalH,
    const int* __restrict__ col, int* __restrict__ deg, int E, int n,
    const float* __restrict__ t, float* __restrict__ tn,
    const float* __restrict__ W, uint* __restrict__ Wpk, int step,
    int ib, int eb) {
  int bid = blockIdx.x;
  int tid = threadIdx.x;
  if (bid < ib) {
    int i = bid * 256 + tid;
    if (i < totalH) {
      float2 v = ((const float2*)x)[i];
      h0[i] = pack_f16(v.x, v.y);
    }
  } else if (bid < ib + eb) {
    int i = (bid - ib) * 256 + tid;
    if (i < E) {
      int c = col[i];
      if ((unsigned)c < (unsigned)n) atomicAdd(&deg[c], 1);
    }
  } else {
    if (tid < D) {
      float vals[16];
      float m = -1e30f;
      for (int k = 0; k < step; ++k) { vals[k] = t[k * D + tid]; m = fmaxf(m, vals[k]); }
      float ssum = 0.f;
      for (int k = 0; k < step; ++k) { vals[k] = expf(vals[k] - m); ssum += vals[k]; }
      float inv = 1.f / ssum;
      for (int k = 0; k < step; ++k) tn[k * D + tid] = vals[k] * inv;
    }
    for (int i = tid; i < O * 64; i += 256) {
      int o = i & 63, dd = i >> 6;  // i = dd*64 + o
      Wpk[i] = pack_f16(W[o * D + 2 * dd], W[o * D + 2 * dd + 1]);
    }
  }
}

// ---------------- single-kernel scan: decoupled lookback ----------------
// Fuses scan1+scan2+scan3. desc[b] packs {flag:32 | value:32};
// flag 0=invalid, 1=aggregate published, 2=inclusive prefix published.
// Requires all blocks co-resident (nb <= MAX_SCAN_BLOCKS guard at launch).

__global__ __launch_bounds__(256) void scan_all_k(
    const int* __restrict__ deg, int* __restrict__ row_ptr, int* __restrict__ cursor,
    float* __restrict__ dinv, ull* __restrict__ desc, int n) {
  __shared__ int s[256];
  __shared__ int sOff;
  int tid = threadIdx.x, bid = blockIdx.x;
  int gid = bid * 256 + tid;
  int dg = (gid < n) ? deg[gid] : 0;
  if (gid < n) dinv[gid] = rsqrtf((float)(dg + 1));
  s[tid] = dg;
  __syncthreads();
  for (int off = 1; off < 256; off <<= 1) {
    int t = (tid >= off) ? s[tid - off] : 0;
    __syncthreads();
    s[tid] += t;
    __syncthreads();
  }
  if (tid == 0) {
    int agg = s[255];
    ull mine = ((ull)(bid == 0 ? 2u : 1u) << 32) | (uint)agg;
    atomicExch(&desc[bid], mine);
    int off = 0;
    if (bid > 0) {
      int j = bid - 1;
      for (;;) {
        ull d = atomicAdd(&desc[j], 0ULL);  // device-scope atomic load
        uint f = (uint)(d >> 32);
        if (f == 0) continue;               // predecessor not ready: spin
        off += (int)(uint)(d & 0xffffffffULL);
        if (f == 2) break;                  // hit a full prefix
        --j;                                // aggregate: keep looking back
      }
      atomicExch(&desc[bid], ((ull)2u << 32) | (uint)(off + agg));
    }
    sOff = off;
  }
  __syncthreads();
  if (gid < n) {
    int r = s[tid] - dg + sOff;  // global exclusive prefix
    row_ptr[gid] = r;
    cursor[gid] = r;
    if (gid == n - 1) row_ptr[n] = r + dg;
  }
}

// ---------------- fallback scan kernels (nb > MAX_SCAN_BLOCKS) ----------------

__global__ void scan1_k(const int* __restrict__ deg, int* __restrict__ row_ptr,
                        int* __restrict__ bsum, float* __restrict__ dinv, int n) {
  __shared__ int s[256];
  int tid = threadIdx.x;
  int gid = blockIdx.x * 256 + tid;
  int dg = (gid < n) ? deg[gid] : 0;
  if (gid < n) dinv[gid] = rsqrtf((float)(dg + 1));
  s[tid] = dg;
  __syncthreads();
  for (int off = 1; off < 256; off <<= 1) {
    int t = (tid >= off) ? s[tid - off] : 0;
    __syncthreads();
    s[tid] += t;
    __syncthreads();
  }
  if (gid < n) row_ptr[gid] = s[tid] - dg;
  if (tid == 255) bsum[blockIdx.x] = s[255];
}

__global__ void scan2_k(int* __restrict__ bsum, int nb) {
  __shared__ int s[512];
  int tid = threadIdx.x;
  int acc = 0;
  // serial-chunked scan over up to 512*chunks blocks
  for (int base = 0; base < nb; base += 512) {
    int v = (base + tid < nb) ? bsum[base + tid] : 0;
    s[tid] = v;
    __syncthreads();
    for (int off = 1; off < 512; off <<= 1) {
      int t = (tid >= off) ? s[tid - off] : 0;
      __syncthreads();
      s[tid] += t;
      __syncthreads();
    }
    if (base + tid < nb) bsum[base + tid] = s[tid] - v + acc;
    __syncthreads();
    acc += s[511];
    __syncthreads();
  }
}

__global__ void scan3_k(const int* __restrict__ bsum, const int* __restrict__ deg,
                        int* __restrict__ row_ptr, int* __restrict__ cursor, int n) {
  int gid = blockIdx.x * 256 + threadIdx.x;
  if (gid < n) {
    int r = row_ptr[gid] + bsum[blockIdx.x];
    row_ptr[gid] = r;
    cursor[gid] = r;
    if (gid == n - 1) row_ptr[n] = r + deg[gid];
  }
}

// ---------------- CSR fill ----------------

__global__ void fill_k(const int* __restrict__ rows, const int* __restrict__ cols,
                       int* __restrict__ cursor, const float* __restrict__ dinv,
                       int2* __restrict__ csr, int E, int n) {
  int i = blockIdx.x * blockDim.x + threadIdx.x;
  if (i >= E) return;
  int u = rows[i], v = cols[i];
  if ((unsigned)v >= (unsigned)n) return;  // must match count skip
  if ((unsigned)u >= (unsigned)n) u = 0;
  int slot = atomicAdd(&cursor[v], 1);
  float nrm = dinv[u] * dinv[v];
  csr[slot] = make_int2(u, __float_as_int(nrm));
}

// ---------------- hop (R1-proven): h_new = A_norm*h_old, paired y ------------
// DO_Y: 0 none | 1 y = tp*h_old + tc*h_new | 2 y += pair | 3 y += tc*h_new

template <int DO_Y>
__global__ __launch_bounds__(256) void hop_f_k(
    const uint* __restrict__ h_old, uint* __restrict__ h_new, uint* __restrict__ y,
    const int* __restrict__ row_ptr, const int2* __restrict__ csr,
    const float* __restrict__ dinv, const float* __restrict__ tprev,
    const float* __restrict__ tcur, int n) {
  int wid = (blockIdx.x * blockDim.x + threadIdx.x) >> 6;
  int lane = threadIdx.x & 63;
  if (wid >= n) return;
  int v = __builtin_amdgcn_readfirstlane(wid);
  float dv = dinv[v];
  float ns = dv * dv;
  uint hp = h_old[(size_t)v * 64 + lane];
  half2_t hv = *(half2_t*)&hp;
  float hx = (float)hv.x, hy = (float)hv.y;
  float ax = ns * hx, ay = ns * hy;
  int beg = __builtin_amdgcn_readfirstlane(row_ptr[v]);
  int end = __builtin_amdgcn_readfirstlane(row_ptr[v + 1]);
  for (int i = beg; i < end; i += UNR) {
    int u[UNR];
    float w[UNR];
#pragma unroll
    for (int j = 0; j < UNR; ++j) {
      int ic = i + j;
      int icl = (ic < end - 1) ? ic : (end - 1);
      int2 e = csr[icl];
      u[j] = e.x;
      w[j] = (ic < end) ? __int_as_float(e.y) : 0.f;
    }
    uint g[UNR];
#pragma unroll
    for (int j = 0; j < UNR; ++j) g[j] = h_old[(size_t)u[j] * 64 + lane];
#pragma unroll
    for (int j = 0; j < UNR; ++j) {
      half2_t h = *(half2_t*)&g[j];
      ax += w[j] * (float)h.x;
      ay += w[j] * (float)h.y;
    }
  }
  h_new[(size_t)v * 64 + lane] = pack_f16(ax, ay);
  if (DO_Y) {
    float yx = 0.f, yy = 0.f;
    if (DO_Y != 3) {
      float2 ta = ((const float2*)tprev)[lane];
      yx = ta.x * hx;
      yy = ta.y * hy;
    }
    float2 tb = ((const float2*)tcur)[lane];
    yx += tb.x * ax;
    yy += tb.y * ay;
    if (DO_Y >= 2) {
      uint yo = y[(size_t)v * 64 + lane];
      half2_t yh = *(half2_t*)&yo;
      yx += (float)yh.x;
      yy += (float)yh.y;
    }
    y[(size_t)v * 64 + lane] = pack_f16(yx, yy);
  }
}

// ---------------- proj from fused y: out = y @ W^T + b ----------------

__global__ __launch_bounds__(256) void proj_y2_k(
    const uint* __restrict__ y, const uint* __restrict__ Wpk,
    const float* __restrict__ b, float* __restrict__ out, int n) {
  __shared__ uint sy[4][64];
  int tid = threadIdx.x;
  int lane = tid & 63, wv = tid >> 6;
  uint wreg[64];
#pragma unroll
  for (int j = 0; j < 64; ++j) wreg[j] = Wpk[j * 64 + lane];  // coalesced (transposed)
  float bias = b[lane];
  int wid = (blockIdx.x * blockDim.x + tid) >> 6;
  int vb = wid * PNW;
  int ve = vb + PNW < n ? vb + PNW : n;
  for (int v = vb; v < ve; ++v) {
    sy[wv][lane] = y[(size_t)v * 64 + lane];  // wave-local broadcast buffer
    float acc = bias;
#pragma unroll
    for (int q = 0; q < 16; ++q) {
      uint4 yq = *(const uint4*)&sy[wv][q * 4];  // broadcast b128 read
      acc = dot2f(yq.x, wreg[q * 4 + 0], acc);
      acc = dot2f(yq.y, wreg[q * 4 + 1], acc);
      acc = dot2f(yq.z, wreg[q * 4 + 2], acc);
      acc = dot2f(yq.w, wreg[q * 4 + 3], acc);
    }
    out[(size_t)v * O + lane] = acc;
  }
}

// ---------------- launch ----------------

extern "C" void kernel_launch(void* const* d_in, const int* in_sizes, int n_in,
                              void* d_out, int out_size, void* d_ws, size_t ws_size,
                              hipStream_t stream) {
  const float* x = (const float*)d_in[0];
  const int* ei = (const int*)d_in[1];
  const float* t = (const float*)d_in[2];
  const float* W = (const float*)d_in[3];
  const float* b = (const float*)d_in[4];
  float* out = (float*)d_out;

  int n = in_sizes[0] / D;
  int E = in_sizes[1] / 2;
  int step = in_sizes[2] / D;  // = 10
  const int* rows = ei;        // sources
  const int* cols = ei + E;    // targets

  int nb1 = (n + 255) / 256;

  char* p = (char*)d_ws;
  auto alloc = [&](size_t bytes) { char* r = p; p += align_up(bytes, 256); return r; };
  int*   deg     = (int*)alloc((size_t)n * 4);
  ull*   desc    = (ull*)alloc((size_t)nb1 * 8);  // adjacent to deg: one memset covers both
  float* dinv    = (float*)alloc((size_t)n * 4);
  int*   row_ptr = (int*)alloc((size_t)(n + 1) * 4);
  int*   cursor  = (int*)alloc((size_t)n * 4);
  int*   bsum    = (int*)alloc(align_up((size_t)nb1 * 4, 256));
  int2*  csr     = (int2*)alloc((size_t)E * 8);
  float* tn      = (float*)alloc((size_t)step * D * 4);
  uint*  Wpk     = (uint*)alloc((size_t)O * 64 * 4);

  size_t NS = (size_t)n * 64;  // uints per h buffer
  uint* h_a  = (uint*)alloc(NS * 4);
  uint* h_b  = (uint*)alloc(NS * 4);
  uint* ybuf = (uint*)alloc(NS * 4);

  // ---- zero deg + scan descriptors in one memset (adjacent allocs) ----
  size_t zlen = (size_t)((char*)(desc + nb1) - (char*)deg);
  hipMemsetAsync(deg, 0, zlen, stream);

  // ---- fused setup: init_h + count_deg + prep in one grid ----
  int ib = (int)((NS + 255) / 256);
  int eb = (E + 255) / 256;
  setup_k<<<ib + eb + 1, 256, 0, stream>>>(x, h_a, (int)NS, cols, deg, E, n,
                                           t, tn, W, Wpk, step, ib, eb);

  // ---- single-dispatch scan (decoupled lookback), fallback if grid too big ----
  if (nb1 <= MAX_SCAN_BLOCKS) {
    scan_all_k<<<nb1, 256, 0, stream>>>(deg, row_ptr, cursor, dinv, desc, n);
  } else {
    scan1_k<<<nb1, 256, 0, stream>>>(deg, row_ptr, bsum, dinv, n);
    scan2_k<<<1, 512, 0, stream>>>(bsum, nb1);
    scan3_k<<<nb1, 256, 0, stream>>>(bsum, deg, row_ptr, cursor, n);
  }

  fill_k<<<(E + 255) / 256, 256, 0, stream>>>(rows, cols, cursor, dinv, csr, E, n);

  // ---- hops (ping-pong h, paired y accumulation; R1-proven kernel) ----
  int hop_blocks = (n + 3) / 4;  // 1 node/wave, 4 waves/block
  uint* ho = h_a;
  uint* hn = h_b;
  for (int k = 1; k < step; ++k) {
    const float* tp = tn + (size_t)(k - 1) * D;
    const float* tc = tn + (size_t)k * D;
    if (k & 1) {
      if (k == 1)
        hop_f_k<1><<<hop_blocks, 256, 0, stream>>>(ho, hn, ybuf, row_ptr, csr, dinv, tp, tc, n);
      else
        hop_f_k<2><<<hop_blocks, 256, 0, stream>>>(ho, hn, ybuf, row_ptr, csr, dinv, tp, tc, n);
    } else if (k == step - 1) {
      // only reached when step is odd: tail single-term accumulation
      hop_f_k<3><<<hop_blocks, 256, 0, stream>>>(ho, hn, ybuf, row_ptr, csr, dinv, tp, tc, n);
    } else {
      hop_f_k<0><<<hop_blocks, 256, 0, stream>>>(ho, hn, ybuf, row_ptr, csr, dinv, tp, tc, n);
    }
    uint* tmp = ho; ho = hn; hn = tmp;
  }

  int proj_blocks = (n + PNW * 4 - 1) / (PNW * 4);
  proj_y2_k<<<proj_blocks, 256, 0, stream>>>(ybuf, Wpk, b, out, n);
}

// Round 5
// 516.180 us; speedup vs baseline: 1.0434x; 1.0286x over previous
//
#include <hip/hip_runtime.h>

typedef _Float16 half2_t __attribute__((ext_vector_type(2)));
typedef unsigned int uint;
typedef unsigned long long ull;

#define D 128
#define O 64
#define UNR 8
#define PNW 8   // nodes per wave in proj
#define MAX_SCAN_BLOCKS 2000  // co-residency guard for lookback scan (8 blk/CU * 256 CU)
#define ZONE_A 1536  // setup blocks: x -> f16 h0 (grid-stride float4)
#define ZONE_B 512   // setup blocks: degree count (grid-stride int4)
#define FILL_BLOCKS 1024

static inline size_t align_up(size_t x, size_t a) { return (x + a - 1) & ~(a - 1); }

__device__ __forceinline__ uint pack_f16(float a, float b) {
  half2_t h;
  h.x = (_Float16)a;
  h.y = (_Float16)b;
  return *(uint*)&h;
}

__device__ __forceinline__ float dot2f(uint a, uint b, float c) {
#if defined(__has_builtin) && __has_builtin(__builtin_amdgcn_fdot2)
  return __builtin_amdgcn_fdot2(*(half2_t*)&a, *(half2_t*)&b, c, false);
#else
  half2_t ha = *(half2_t*)&a, hb = *(half2_t*)&b;
  return c + (float)ha.x * (float)hb.x + (float)ha.y * (float)hb.y;
#endif
}

// ---------------- fused setup mega-kernel (grid-stride zones) ----------------
// zone A [0, ZONE_A)          : x -> f16 h0, float4 loads, uint2 stores
// zone B [ZONE_A, ZONE_A+ZONE_B): degree count, int4 loads, 4 atomics/thread
// zone C [ZONE_A+ZONE_B]      : softmax(t) + pack W

__global__ __launch_bounds__(256) void setup_k(
    const float* __restrict__ x, uint* __restrict__ h0, int nF4,
    const int* __restrict__ col, int* __restrict__ deg, int E, int n,
    const float* __restrict__ t, float* __restrict__ tn,
    const float* __restrict__ W, uint* __restrict__ Wpk, int step) {
  int bid = blockIdx.x;
  int tid = threadIdx.x;
  if (bid < ZONE_A) {
    int stride = ZONE_A * 256;
    for (int i = bid * 256 + tid; i < nF4; i += stride) {
      float4 v = ((const float4*)x)[i];
      uint2 o;
      o.x = pack_f16(v.x, v.y);
      o.y = pack_f16(v.z, v.w);
      ((uint2*)h0)[i] = o;
    }
  } else if (bid < ZONE_A + ZONE_B) {
    int b = bid - ZONE_A;
    int stride = ZONE_B * 256;
    int nE4 = E >> 2;
    for (int i = b * 256 + tid; i < nE4; i += stride) {
      int4 c = ((const int4*)col)[i];
      if ((unsigned)c.x < (unsigned)n) atomicAdd(&deg[c.x], 1);
      if ((unsigned)c.y < (unsigned)n) atomicAdd(&deg[c.y], 1);
      if ((unsigned)c.z < (unsigned)n) atomicAdd(&deg[c.z], 1);
      if ((unsigned)c.w < (unsigned)n) atomicAdd(&deg[c.w], 1);
    }
    if (b == 0 && tid < (E & 3)) {
      int c = col[(nE4 << 2) + tid];
      if ((unsigned)c < (unsigned)n) atomicAdd(&deg[c], 1);
    }
  } else {
    if (tid < D) {
      float vals[16];
      float m = -1e30f;
      for (int k = 0; k < step; ++k) { vals[k] = t[k * D + tid]; m = fmaxf(m, vals[k]); }
      float ssum = 0.f;
      for (int k = 0; k < step; ++k) { vals[k] = expf(vals[k] - m); ssum += vals[k]; }
      float inv = 1.f / ssum;
      for (int k = 0; k < step; ++k) tn[k * D + tid] = vals[k] * inv;
    }
    for (int i = tid; i < O * 64; i += 256) {
      int o = i & 63, dd = i >> 6;  // i = dd*64 + o
      Wpk[i] = pack_f16(W[o * D + 2 * dd], W[o * D + 2 * dd + 1]);
    }
  }
}

// ---------------- single-kernel scan: decoupled lookback ----------------
// desc[b] packs {flag:32 | value:32}; 0=invalid 1=aggregate 2=inclusive prefix.
// Requires all blocks co-resident (nb <= MAX_SCAN_BLOCKS guard at launch).

__global__ __launch_bounds__(256) void scan_all_k(
    const int* __restrict__ deg, int* __restrict__ row_ptr, int* __restrict__ cursor,
    float* __restrict__ dinv, ull* __restrict__ desc, int n) {
  __shared__ int s[256];
  __shared__ int sOff;
  int tid = threadIdx.x, bid = blockIdx.x;
  int gid = bid * 256 + tid;
  int dg = (gid < n) ? deg[gid] : 0;
  if (gid < n) dinv[gid] = rsqrtf((float)(dg + 1));
  s[tid] = dg;
  __syncthreads();
  for (int off = 1; off < 256; off <<= 1) {
    int t = (tid >= off) ? s[tid - off] : 0;
    __syncthreads();
    s[tid] += t;
    __syncthreads();
  }
  if (tid == 0) {
    int agg = s[255];
    ull mine = ((ull)(bid == 0 ? 2u : 1u) << 32) | (uint)agg;
    atomicExch(&desc[bid], mine);
    int off = 0;
    if (bid > 0) {
      int j = bid - 1;
      for (;;) {
        ull d = atomicAdd(&desc[j], 0ULL);  // device-scope atomic load
        uint f = (uint)(d >> 32);
        if (f == 0) continue;               // predecessor not ready: spin
        off += (int)(uint)(d & 0xffffffffULL);
        if (f == 2) break;                  // hit a full prefix
        --j;                                // aggregate: keep looking back
      }
      atomicExch(&desc[bid], ((ull)2u << 32) | (uint)(off + agg));
    }
    sOff = off;
  }
  __syncthreads();
  if (gid < n) {
    int r = s[tid] - dg + sOff;  // global exclusive prefix
    row_ptr[gid] = r;
    cursor[gid] = r;
    if (gid == n - 1) row_ptr[n] = r + dg;
  }
}

// ---------------- fallback scan kernels (nb > MAX_SCAN_BLOCKS) ----------------

__global__ void scan1_k(const int* __restrict__ deg, int* __restrict__ row_ptr,
                        int* __restrict__ bsum, float* __restrict__ dinv, int n) {
  __shared__ int s[256];
  int tid = threadIdx.x;
  int gid = blockIdx.x * 256 + tid;
  int dg = (gid < n) ? deg[gid] : 0;
  if (gid < n) dinv[gid] = rsqrtf((float)(dg + 1));
  s[tid] = dg;
  __syncthreads();
  for (int off = 1; off < 256; off <<= 1) {
    int t = (tid >= off) ? s[tid - off] : 0;
    __syncthreads();
    s[tid] += t;
    __syncthreads();
  }
  if (gid < n) row_ptr[gid] = s[tid] - dg;
  if (tid == 255) bsum[blockIdx.x] = s[255];
}

__global__ void scan2_k(int* __restrict__ bsum, int nb) {
  __shared__ int s[512];
  int tid = threadIdx.x;
  int acc = 0;
  for (int base = 0; base < nb; base += 512) {
    int v = (base + tid < nb) ? bsum[base + tid] : 0;
    s[tid] = v;
    __syncthreads();
    for (int off = 1; off < 512; off <<= 1) {
      int t = (tid >= off) ? s[tid - off] : 0;
      __syncthreads();
      s[tid] += t;
      __syncthreads();
    }
    if (base + tid < nb) bsum[base + tid] = s[tid] - v + acc;
    __syncthreads();
    acc += s[511];
    __syncthreads();
  }
}

__global__ void scan3_k(const int* __restrict__ bsum, const int* __restrict__ deg,
                        int* __restrict__ row_ptr, int* __restrict__ cursor, int n) {
  int gid = blockIdx.x * 256 + threadIdx.x;
  if (gid < n) {
    int r = row_ptr[gid] + bsum[blockIdx.x];
    row_ptr[gid] = r;
    cursor[gid] = r;
    if (gid == n - 1) row_ptr[n] = r + deg[gid];
  }
}

// ---------------- CSR fill (grid-stride, int4 edge reads) ----------------

__device__ __forceinline__ void fill_one(int u, int v, int n, int* cursor,
                                         const float* dinv, int2* csr) {
  if ((unsigned)v >= (unsigned)n) return;  // must match count skip
  if ((unsigned)u >= (unsigned)n) u = 0;
  int slot = atomicAdd(&cursor[v], 1);
  float nrm = dinv[u] * dinv[v];
  csr[slot] = make_int2(u, __float_as_int(nrm));
}

__global__ __launch_bounds__(256) void fill_k(
    const int* __restrict__ rows, const int* __restrict__ cols,
    int* __restrict__ cursor, const float* __restrict__ dinv,
    int2* __restrict__ csr, int E, int n) {
  int stride = gridDim.x * 256;
  int nE4 = E >> 2;
  for (int i = blockIdx.x * 256 + threadIdx.x; i < nE4; i += stride) {
    int4 u4 = ((const int4*)rows)[i];
    int4 v4 = ((const int4*)cols)[i];
    fill_one(u4.x, v4.x, n, cursor, dinv, csr);
    fill_one(u4.y, v4.y, n, cursor, dinv, csr);
    fill_one(u4.z, v4.z, n, cursor, dinv, csr);
    fill_one(u4.w, v4.w, n, cursor, dinv, csr);
  }
  if (blockIdx.x == 0 && threadIdx.x < (E & 3)) {
    int e = (nE4 << 2) + threadIdx.x;
    fill_one(rows[e], cols[e], n, cursor, dinv, csr);
  }
}

// ---------------- hop (R1-proven): h_new = A_norm*h_old, paired y ------------
// DO_Y: 0 none | 1 y = tp*h_old + tc*h_new | 2 y += pair | 3 y += tc*h_new

template <int DO_Y>
__global__ __launch_bounds__(256) void hop_f_k(
    const uint* __restrict__ h_old, uint* __restrict__ h_new, uint* __restrict__ y,
    const int* __restrict__ row_ptr, const int2* __restrict__ csr,
    const float* __restrict__ dinv, const float* __restrict__ tprev,
    const float* __restrict__ tcur, int n) {
  int wid = (blockIdx.x * blockDim.x + threadIdx.x) >> 6;
  int lane = threadIdx.x & 63;
  if (wid >= n) return;
  int v = __builtin_amdgcn_readfirstlane(wid);
  float dv = dinv[v];
  float ns = dv * dv;
  uint hp = h_old[(size_t)v * 64 + lane];
  half2_t hv = *(half2_t*)&hp;
  float hx = (float)hv.x, hy = (float)hv.y;
  float ax = ns * hx, ay = ns * hy;
  int beg = __builtin_amdgcn_readfirstlane(row_ptr[v]);
  int end = __builtin_amdgcn_readfirstlane(row_ptr[v + 1]);
  for (int i = beg; i < end; i += UNR) {
    int u[UNR];
    float w[UNR];
#pragma unroll
    for (int j = 0; j < UNR; ++j) {
      int ic = i + j;
      int icl = (ic < end - 1) ? ic : (end - 1);
      int2 e = csr[icl];
      u[j] = e.x;
      w[j] = (ic < end) ? __int_as_float(e.y) : 0.f;
    }
    uint g[UNR];
#pragma unroll
    for (int j = 0; j < UNR; ++j) g[j] = h_old[(size_t)u[j] * 64 + lane];
#pragma unroll
    for (int j = 0; j < UNR; ++j) {
      half2_t h = *(half2_t*)&g[j];
      ax += w[j] * (float)h.x;
      ay += w[j] * (float)h.y;
    }
  }
  h_new[(size_t)v * 64 + lane] = pack_f16(ax, ay);
  if (DO_Y) {
    float yx = 0.f, yy = 0.f;
    if (DO_Y != 3) {
      float2 ta = ((const float2*)tprev)[lane];
      yx = ta.x * hx;
      yy = ta.y * hy;
    }
    float2 tb = ((const float2*)tcur)[lane];
    yx += tb.x * ax;
    yy += tb.y * ay;
    if (DO_Y >= 2) {
      uint yo = y[(size_t)v * 64 + lane];
      half2_t yh = *(half2_t*)&yo;
      yx += (float)yh.x;
      yy += (float)yh.y;
    }
    y[(size_t)v * 64 + lane] = pack_f16(yx, yy);
  }
}

// ---------------- proj from fused y: out = y @ W^T + b ----------------

__global__ __launch_bounds__(256) void proj_y2_k(
    const uint* __restrict__ y, const uint* __restrict__ Wpk,
    const float* __restrict__ b, float* __restrict__ out, int n) {
  __shared__ uint sy[4][64];
  int tid = threadIdx.x;
  int lane = tid & 63, wv = tid >> 6;
  uint wreg[64];
#pragma unroll
  for (int j = 0; j < 64; ++j) wreg[j] = Wpk[j * 64 + lane];  // coalesced (transposed)
  float bias = b[lane];
  int wid = (blockIdx.x * blockDim.x + tid) >> 6;
  int vb = wid * PNW;
  int ve = vb + PNW < n ? vb + PNW : n;
  for (int v = vb; v < ve; ++v) {
    sy[wv][lane] = y[(size_t)v * 64 + lane];  // wave-local broadcast buffer
    float acc = bias;
#pragma unroll
    for (int q = 0; q < 16; ++q) {
      uint4 yq = *(const uint4*)&sy[wv][q * 4];  // broadcast b128 read
      acc = dot2f(yq.x, wreg[q * 4 + 0], acc);
      acc = dot2f(yq.y, wreg[q * 4 + 1], acc);
      acc = dot2f(yq.z, wreg[q * 4 + 2], acc);
      acc = dot2f(yq.w, wreg[q * 4 + 3], acc);
    }
    out[(size_t)v * O + lane] = acc;
  }
}

// ---------------- launch ----------------

extern "C" void kernel_launch(void* const* d_in, const int* in_sizes, int n_in,
                              void* d_out, int out_size, void* d_ws, size_t ws_size,
                              hipStream_t stream) {
  const float* x = (const float*)d_in[0];
  const int* ei = (const int*)d_in[1];
  const float* t = (const float*)d_in[2];
  const float* W = (const float*)d_in[3];
  const float* b = (const float*)d_in[4];
  float* out = (float*)d_out;

  int n = in_sizes[0] / D;
  int E = in_sizes[1] / 2;
  int step = in_sizes[2] / D;  // = 10
  const int* rows = ei;        // sources
  const int* cols = ei + E;    // targets

  int nb1 = (n + 255) / 256;

  char* p = (char*)d_ws;
  auto alloc = [&](size_t bytes) { char* r = p; p += align_up(bytes, 256); return r; };
  int*   deg     = (int*)alloc((size_t)n * 4);
  ull*   desc    = (ull*)alloc((size_t)nb1 * 8);  // adjacent to deg: one memset covers both
  float* dinv    = (float*)alloc((size_t)n * 4);
  int*   row_ptr = (int*)alloc((size_t)(n + 1) * 4);
  int*   cursor  = (int*)alloc((size_t)n * 4);
  int*   bsum    = (int*)alloc(align_up((size_t)nb1 * 4, 256));
  int2*  csr     = (int2*)alloc((size_t)E * 8);
  float* tn      = (float*)alloc((size_t)step * D * 4);
  uint*  Wpk     = (uint*)alloc((size_t)O * 64 * 4);

  size_t NS = (size_t)n * 64;  // uints per h buffer
  uint* h_a  = (uint*)alloc(NS * 4);
  uint* h_b  = (uint*)alloc(NS * 4);
  uint* ybuf = (uint*)alloc(NS * 4);

  // ---- zero deg + scan descriptors in one memset (adjacent allocs) ----
  size_t zlen = (size_t)((char*)(desc + nb1) - (char*)deg);
  hipMemsetAsync(deg, 0, zlen, stream);

  // ---- fused setup: init_h + count_deg + prep, grid-stride zones ----
  int nF4 = (int)(NS >> 1);  // x float4 count == h uint2 count
  setup_k<<<ZONE_A + ZONE_B + 1, 256, 0, stream>>>(x, h_a, nF4, cols, deg, E, n,
                                                   t, tn, W, Wpk, step);

  // ---- single-dispatch scan (decoupled lookback), fallback if grid too big ----
  if (nb1 <= MAX_SCAN_BLOCKS) {
    scan_all_k<<<nb1, 256, 0, stream>>>(deg, row_ptr, cursor, dinv, desc, n);
  } else {
    scan1_k<<<nb1, 256, 0, stream>>>(deg, row_ptr, bsum, dinv, n);
    scan2_k<<<1, 512, 0, stream>>>(bsum, nb1);
    scan3_k<<<nb1, 256, 0, stream>>>(bsum, deg, row_ptr, cursor, n);
  }

  fill_k<<<FILL_BLOCKS, 256, 0, stream>>>(rows, cols, cursor, dinv, csr, E, n);

  // ---- hops (ping-pong h, paired y accumulation; R1-proven kernel) ----
  int hop_blocks = (n + 3) / 4;  // 1 node/wave, 4 waves/block
  uint* ho = h_a;
  uint* hn = h_b;
  for (int k = 1; k < step; ++k) {
    const float* tp = tn + (size_t)(k - 1) * D;
    const float* tc = tn + (size_t)k * D;
    if (k & 1) {
      if (k == 1)
        hop_f_k<1><<<hop_blocks, 256, 0, stream>>>(ho, hn, ybuf, row_ptr, csr, dinv, tp, tc, n);
      else
        hop_f_k<2><<<hop_blocks, 256, 0, stream>>>(ho, hn, ybuf, row_ptr, csr, dinv, tp, tc, n);
    } else if (k == step - 1) {
      // only reached when step is odd: tail single-term accumulation
      hop_f_k<3><<<hop_blocks, 256, 0, stream>>>(ho, hn, ybuf, row_ptr, csr, dinv, tp, tc, n);
    } else {
      hop_f_k<0><<<hop_blocks, 256, 0, stream>>>(ho, hn, ybuf, row_ptr, csr, dinv, tp, tc, n);
    }
    uint* tmp = ho; ho = hn; hn = tmp;
  }

  int proj_blocks = (n + PNW * 4 - 1) / (PNW * 4);
  proj_y2_k<<<proj_blocks, 256, 0, stream>>>(ybuf, Wpk, b, out, n);
}